// Round 1
// baseline (97.882 us; speedup 1.0000x reference)
//
#include <hip/hip_runtime.h>

#define NROB 32
#define SEQ 12
#define LOBS 52
#define HID 256
#define LOUT 2
#define BATCH 1024
#define KIN (SEQ * LOBS)   // 624
#define KA (KIN + SEQ)     // 648: 624 masked obs cols + 12 mask-indicator cols (bias)
#define SPB 8              // samples per chunk
#define MAXCH 160          // >= max possible chunks (<=156)
#define ATSZ (KA * SPB)    // 5184 floats per chunk

// meta layout in ws (ints)
#define M_NCH 0
#define M_CSTART 1     // [32] first chunk index of robot r
#define M_SOFF 33      // [32] first sorted-sample offset of robot r
#define M_CNT 65       // [32] sample count of robot r
#define M_CHROB 97     // [160] chunk -> robot
#define M_PERM 257     // [1024] sorted order -> sample index
#define AT_OFF 2048    // float offset of A' in ws (8KB for meta)

__device__ __forceinline__ void fma4(float4& a, const float4 w, const float s) {
  a.x = fmaf(w.x, s, a.x);
  a.y = fmaf(w.y, s, a.y);
  a.z = fmaf(w.z, s, a.z);
  a.w = fmaf(w.w, s, a.w);
}

__global__ __launch_bounds__(1024) void k_sort(const int* __restrict__ ids,
                                               int* __restrict__ meta) {
  __shared__ int hist[NROB], cnt2[NROB], s_soff[NROB];
  const int t = threadIdx.x;
  if (t < NROB) { hist[t] = 0; cnt2[t] = 0; }
  __syncthreads();
  const int myid = ids[t];
  atomicAdd(&hist[myid], 1);
  __syncthreads();
  if (t == 0) {
    int off = 0, ch = 0;
    for (int r = 0; r < NROB; r++) {
      const int c = hist[r];
      s_soff[r] = off;
      meta[M_SOFF + r] = off;
      meta[M_CSTART + r] = ch;
      meta[M_CNT + r] = c;
      const int nch = (c + SPB - 1) / SPB;
      for (int q = 0; q < nch; q++) meta[M_CHROB + ch + q] = r;
      off += c;
      ch += nch;
    }
    meta[M_NCH] = ch;
  }
  __syncthreads();
  const int rank = atomicAdd(&cnt2[myid], 1);
  meta[M_PERM + s_soff[myid] + rank] = t;  // intra-bucket order arbitrary; output invariant
}

// Build sorted, masked, per-chunk-transposed activations A'[ch][k][j]
__global__ __launch_bounds__(256) void k_build(const float* __restrict__ obs,
                                               const int* __restrict__ mask,
                                               const int* __restrict__ meta,
                                               float* __restrict__ At) {
  const int ch = blockIdx.x;
  if (ch >= meta[M_NCH]) return;
  const int r = meta[M_CHROB + ch];
  const int base = (ch - meta[M_CSTART + r]) * SPB;
  const int cnt = meta[M_CNT + r];
  const int soff = meta[M_SOFF + r];
  float* dst = At + (size_t)ch * ATSZ;
  for (int i = threadIdx.x; i < ATSZ; i += 256) {
    const int k = i >> 3, j = i & 7;
    const int rank = base + j;
    float val = 0.f;
    if (rank < cnt) {
      const int b = meta[M_PERM + soff + rank];
      const int s = (k < KIN) ? (k / LOBS) : (k - KIN);
      if (mask[b * SEQ + s] == 0) val = (k < KIN) ? obs[b * KIN + k] : 1.0f;
    }
    dst[i] = val;  // always written: dummy rows zeroed every call (ws is 0xAA-poisoned)
  }
}

__device__ __forceinline__ void dense_layer(const float* __restrict__ Wp,
                                            const float* __restrict__ bp,
                                            const float* src, float* dst,
                                            const int h0, const int j0) {
  float4 acc0 = {0.f, 0.f, 0.f, 0.f}, acc1 = {0.f, 0.f, 0.f, 0.f};
#pragma unroll 8
  for (int k = 0; k < HID; k++) {
    const float2 av = *(const float2*)&src[k * 8 + j0];
    const float4 w = *(const float4*)(Wp + k * HID + h0);
    fma4(acc0, w, av.x);
    fma4(acc1, w, av.y);
  }
  const float4 bv = *(const float4*)(bp + h0);
  dst[(h0 + 0) * 8 + j0] = fmaxf(acc0.x + bv.x, 0.f);
  dst[(h0 + 1) * 8 + j0] = fmaxf(acc0.y + bv.y, 0.f);
  dst[(h0 + 2) * 8 + j0] = fmaxf(acc0.z + bv.z, 0.f);
  dst[(h0 + 3) * 8 + j0] = fmaxf(acc0.w + bv.w, 0.f);
  dst[(h0 + 0) * 8 + j0 + 1] = fmaxf(acc1.x + bv.x, 0.f);
  dst[(h0 + 1) * 8 + j0 + 1] = fmaxf(acc1.y + bv.y, 0.f);
  dst[(h0 + 2) * 8 + j0 + 1] = fmaxf(acc1.z + bv.z, 0.f);
  dst[(h0 + 3) * 8 + j0 + 1] = fmaxf(acc1.w + bv.w, 0.f);
  __syncthreads();
}

__global__ __launch_bounds__(256) void k_mlp(
    const float* __restrict__ Wi, const float* __restrict__ bi,
    const float* __restrict__ W1, const float* __restrict__ b1,
    const float* __restrict__ W2, const float* __restrict__ b2,
    const float* __restrict__ W3, const float* __restrict__ b3,
    const float* __restrict__ Wo, const float* __restrict__ bo,
    const int* __restrict__ meta, const float* __restrict__ At,
    float* __restrict__ out) {
  const int ch = blockIdx.x;
  if (ch >= meta[M_NCH]) return;
  const int r = meta[M_CHROB + ch];
  __shared__ float a_t[ATSZ];
  __shared__ float eA[HID * SPB];
  __shared__ float eB[HID * SPB];
  const int t = threadIdx.x;
  {
    const float4* src = (const float4*)(At + (size_t)ch * ATSZ);
    float4* d4 = (float4*)a_t;
    for (int i = t; i < ATSZ / 4; i += 256) d4[i] = src[i];
  }
  __syncthreads();
  const int jg = t & 3, cg = t >> 2;
  const int h0 = cg * 4, j0 = jg * 2;

  // ---- stage 1: emb = relu(A' @ [Wi; bi]) ----
  {
    float4 acc0 = {0.f, 0.f, 0.f, 0.f}, acc1 = {0.f, 0.f, 0.f, 0.f};
    const float* Wr = Wi + (size_t)r * KIN * HID;
#pragma unroll 8
    for (int k = 0; k < KIN; k++) {
      const float2 av = *(const float2*)&a_t[k * 8 + j0];
      const float4 w = *(const float4*)(Wr + (size_t)k * HID + h0);
      fma4(acc0, w, av.x);
      fma4(acc1, w, av.y);
    }
    const float* br = bi + r * SEQ * HID;
#pragma unroll
    for (int k = 0; k < SEQ; k++) {
      const float2 av = *(const float2*)&a_t[(KIN + k) * 8 + j0];
      const float4 w = *(const float4*)(br + k * HID + h0);
      fma4(acc0, w, av.x);
      fma4(acc1, w, av.y);
    }
    eA[(h0 + 0) * 8 + j0] = fmaxf(acc0.x, 0.f);
    eA[(h0 + 1) * 8 + j0] = fmaxf(acc0.y, 0.f);
    eA[(h0 + 2) * 8 + j0] = fmaxf(acc0.z, 0.f);
    eA[(h0 + 3) * 8 + j0] = fmaxf(acc0.w, 0.f);
    eA[(h0 + 0) * 8 + j0 + 1] = fmaxf(acc1.x, 0.f);
    eA[(h0 + 1) * 8 + j0 + 1] = fmaxf(acc1.y, 0.f);
    eA[(h0 + 2) * 8 + j0 + 1] = fmaxf(acc1.z, 0.f);
    eA[(h0 + 3) * 8 + j0 + 1] = fmaxf(acc1.w, 0.f);
    __syncthreads();
  }

  // ---- hidden layers ----
  dense_layer(W1 + (size_t)r * HID * HID, b1 + r * HID, eA, eB, h0, j0);
  dense_layer(W2 + (size_t)r * HID * HID, b2 + r * HID, eB, eA, h0, j0);
  dense_layer(W3 + (size_t)r * HID * HID, b3 + r * HID, eA, eB, h0, j0);

  // ---- output hypernetwork: out[j][s][d] = emb[j] . Wo[r][s][:][d] + bo ----
  if (t < SPB * SEQ * LOUT) {  // 192 threads
    const int j = t & 7, oc = t >> 3;
    const int s = oc >> 1, d = oc & 1;
    const float* Wop = Wo + ((size_t)(r * SEQ + s) * HID) * LOUT + d;
    float acc = bo[(r * SEQ + s) * LOUT + d];
#pragma unroll 8
    for (int k = 0; k < HID; k++) acc = fmaf(eB[k * 8 + j], Wop[k * 2], acc);
    const int base = (ch - meta[M_CSTART + r]) * SPB;
    const int rank = base + j;
    if (rank < meta[M_CNT + r]) {
      const int b = meta[M_PERM + meta[M_SOFF + r] + rank];
      out[b * (SEQ * LOUT) + oc] = acc;
    }
  }
}

extern "C" void kernel_launch(void* const* d_in, const int* in_sizes, int n_in,
                              void* d_out, int out_size, void* d_ws, size_t ws_size,
                              hipStream_t stream) {
  const float* obs = (const float*)d_in[0];
  const int* mask = (const int*)d_in[1];
  const int* ids = (const int*)d_in[2];
  const float* Wi = (const float*)d_in[3];
  const float* bi = (const float*)d_in[4];
  const float* W1 = (const float*)d_in[5];
  const float* b1 = (const float*)d_in[6];
  const float* W2 = (const float*)d_in[7];
  const float* b2 = (const float*)d_in[8];
  const float* W3 = (const float*)d_in[9];
  const float* b3 = (const float*)d_in[10];
  const float* Wo = (const float*)d_in[11];
  const float* bo = (const float*)d_in[12];
  float* out = (float*)d_out;
  int* meta = (int*)d_ws;
  float* At = (float*)d_ws + AT_OFF;

  hipLaunchKernelGGL(k_sort, dim3(1), dim3(1024), 0, stream, ids, meta);
  hipLaunchKernelGGL(k_build, dim3(MAXCH), dim3(256), 0, stream, obs, mask, meta, At);
  hipLaunchKernelGGL(k_mlp, dim3(MAXCH), dim3(256), 0, stream, Wi, bi, W1, b1, W2,
                     b2, W3, b3, Wo, bo, meta, At, out);
}